// Round 3
// baseline (1163.877 us; speedup 1.0000x reference)
//
#include <hip/hip_runtime.h>
#include <math.h>

#define H 10
#define BATCH 16384
#define NPAIRS 1024   // T/2
#define EPW 6         // sequences per 64-lane wave, 60 active lanes
#define GSTRIDE 12    // LDS floats per group (pad 10 -> 12: conflict-free b128 reads)

#define LOG2E 1.44269504088896340736f

#if __has_builtin(__builtin_amdgcn_exp2f)
#define EXP2(x) __builtin_amdgcn_exp2f(x)
#else
#define EXP2(x) exp2f(x)
#endif

typedef float v2f __attribute__((ext_vector_type(2)));

__device__ __forceinline__ float fast_rcp(float x) { return __builtin_amdgcn_rcpf(x); }

// Packed dual-fp32 ops (VOP3P, gfx90a+). Guaranteed via inline asm: halves the
// issue cost of the Whh dot products and halves the k-chain depth.
__device__ __forceinline__ v2f pk_mul(v2f a, v2f b) {
    v2f d;
    asm("v_pk_mul_f32 %0, %1, %2" : "=v"(d) : "v"(a), "v"(b));
    return d;
}
__device__ __forceinline__ v2f pk_fma(v2f a, v2f b, v2f c) {
    v2f d;
    asm("v_pk_fma_f32 %0, %1, %2, %3" : "=v"(d) : "v"(a), "v"(b), "v"(c));
    return d;
}

// waves_per_eu(2,3): tell the allocator occupancy is capped at 3 waves/SIMD
// (170-VGPR budget) so the ~150 live values (100 weights + working set) stay
// in ARCH VGPRs. launch_bounds(64,2) alone did NOT stop AGPR parking: rocprof
// showed VGPR_Count=72 with ~140 live -> ~80 v_accvgpr_read per cell of bloat.
// 3 waves/SIMD still covers the 2731-wave grid (2.67/SIMD demand).
__global__ void __launch_bounds__(64) __attribute__((amdgpu_waves_per_eu(2, 3)))
lstm_kernel(const float* __restrict__ x,
            const float* __restrict__ WihA, const float* __restrict__ WhhA,
            const float* __restrict__ bihA, const float* __restrict__ bhhA,
            const float* __restrict__ WihB, const float* __restrict__ WhhB,
            const float* __restrict__ bihB, const float* __restrict__ bhhB,
            const float* __restrict__ Wlin, const float* __restrict__ blin,
            float* __restrict__ out)
{
    const int lane    = threadIdx.x;          // block = 1 wave
    const int e_local = lane / H;             // 0..6 (6 => spare lanes)
    const int j       = lane - e_local * H;   // hidden unit owned by this lane
    const bool active = lane < EPW * H;
    const int elem    = blockIdx.x * EPW + e_local;
    const bool valid  = active && (elem < BATCH);
    const int jj      = active ? j : 0;
    const int elem_c  = valid ? elem : 0;

    // h-broadcast buffer: group g's h vector at hbuf[g*12 .. g*12+9].
    __shared__ __align__(16) float hbuf[84];
    const int waddr = active ? (e_local * GSTRIDE + j) : (72 + (lane - 60));
    const int rbase = e_local * GSTRIDE;      // inactive: 72, reads stay < 84

    // Per-lane weights: lane j owns gate rows {j, H+j, 2H+j, 3H+j}.
    // Pre-scaled: sigmoid gates (i,f,o) by -log2e, tanh gate (g) by +2log2e.
    // Whh packed as (k, k+1) float2 pairs to feed v_pk_fma_f32 directly.
    v2f wA2[4][5], wB2[4][5];
    float bA[4], bB[4], wxA0[4], wxA1[4], wxB[4];
#pragma unroll
    for (int g = 0; g < 4; ++g) {
        const float s = (g == 2) ? (2.0f * LOG2E) : (-LOG2E);
        const int row = g * H + jj;
        bA[g]   = s * (bihA[row] + bhhA[row]);
        bB[g]   = s * (bihB[row] + bhhB[row]);
        wxA0[g] = s * WihA[row * 2 + 0];
        wxA1[g] = s * WihA[row * 2 + 1];
        wxB[g]  = s * WihB[row];
#pragma unroll
        for (int m = 0; m < 5; ++m) {
            wA2[g][m] = (v2f){s * WhhA[row * H + 2 * m], s * WhhA[row * H + 2 * m + 1]};
            wB2[g][m] = (v2f){s * WhhB[row * H + 2 * m], s * WhhB[row * H + 2 * m + 1]};
        }
    }
    // Pin as opaque register values (defeats rematerialization).
#pragma unroll
    for (int g = 0; g < 4; ++g) {
        asm volatile("" : "+v"(bA[g]), "+v"(bB[g]), "+v"(wxA0[g]),
                          "+v"(wxA1[g]), "+v"(wxB[g]));
#pragma unroll
        for (int m = 0; m < 5; ++m) {
            asm volatile("" : "+v"(wA2[g][m]), "+v"(wB2[g][m]));
        }
    }

    const float4* __restrict__ xr = (const float4*)x + (size_t)elem_c * NPAIRS;

    float h = 0.0f, c = 0.0f;
    float4 xp = xr[0];                        // prefetched current pair

#pragma unroll 2
    for (int p = 0; p < NPAIRS; ++p) {
        const int pn = (p + 1 < NPAIRS) ? (p + 1) : p;
        const float4 xnext = xr[pn];          // off the critical h->h chain

        // ================= cell B: input = x[:, 2p, :1] =================
        {
            hbuf[waddr] = h;                  // start LDS round-trip early
            const float b0 = fmaf(wxB[0], xp.x, bB[0]);
            const float b1 = fmaf(wxB[1], xp.x, bB[1]);
            const float b2 = fmaf(wxB[2], xp.x, bB[2]);
            const float b3 = fmaf(wxB[3], xp.x, bB[3]);
            const float4 ha = *reinterpret_cast<const float4*>(&hbuf[rbase]);
            const float4 hb = *reinterpret_cast<const float4*>(&hbuf[rbase + 4]);
            const float2 hc = *reinterpret_cast<const float2*>(&hbuf[rbase + 8]);
            const v2f h01 = (v2f){ha.x, ha.y}, h23 = (v2f){ha.z, ha.w};
            const v2f h45 = (v2f){hb.x, hb.y}, h67 = (v2f){hb.z, hb.w};
            const v2f h89 = (v2f){hc.x, hc.y};

            v2f a0 = pk_mul(wB2[0][0], h01);
            v2f a1 = pk_mul(wB2[1][0], h01);
            v2f a2 = pk_mul(wB2[2][0], h01);
            v2f a3 = pk_mul(wB2[3][0], h01);
            a0 = pk_fma(wB2[0][1], h23, a0); a1 = pk_fma(wB2[1][1], h23, a1);
            a2 = pk_fma(wB2[2][1], h23, a2); a3 = pk_fma(wB2[3][1], h23, a3);
            a0 = pk_fma(wB2[0][2], h45, a0); a1 = pk_fma(wB2[1][2], h45, a1);
            a2 = pk_fma(wB2[2][2], h45, a2); a3 = pk_fma(wB2[3][2], h45, a3);
            a0 = pk_fma(wB2[0][3], h67, a0); a1 = pk_fma(wB2[1][3], h67, a1);
            a2 = pk_fma(wB2[2][3], h67, a2); a3 = pk_fma(wB2[3][3], h67, a3);
            a0 = pk_fma(wB2[0][4], h89, a0); a1 = pk_fma(wB2[1][4], h89, a1);
            a2 = pk_fma(wB2[2][4], h89, a2); a3 = pk_fma(wB2[3][4], h89, a3);

            const float y0 = (a0.x + a0.y) + b0;   // i (scaled -log2e)
            const float y1 = (a1.x + a1.y) + b1;   // f (scaled -log2e)
            const float y2 = (a2.x + a2.y) + b2;   // g (scaled +2log2e)
            const float y3 = (a3.x + a3.y) + b3;   // o (scaled -log2e)

            // sigm(f)*c + sigm(i)*tanh(g) with ONE rcp (common denominator):
            // cn = [c*d1 + sign(y2)*(1-eg)*opf] / (opf*d1)
            const float ef = EXP2(y1);
            const float ei = EXP2(y0);
            const float eg = EXP2(-__builtin_fabsf(y2));
            const float eo = EXP2(y3);
            const float opf = 1.0f + ef;
            const float d1 = (1.0f + ei) * (1.0f + eg);
            const float tg = __builtin_copysignf((1.0f - eg) * opf, y2);
            const float num = fmaf(c, d1, tg);
            const float cn = num * fast_rcp(opf * d1);
            const float ec = EXP2((-2.0f * LOG2E) * __builtin_fabsf(cn));
            const float d2 = (1.0f + eo) * (1.0f + ec);
            h = __builtin_copysignf((1.0f - ec) * fast_rcp(d2), cn);
            c = cn;
        }

        // ================= cell A: input = x[:, 2p+1, :] =================
        {
            hbuf[waddr] = h;
            const float b0 = fmaf(wxA1[0], xp.w, fmaf(wxA0[0], xp.z, bA[0]));
            const float b1 = fmaf(wxA1[1], xp.w, fmaf(wxA0[1], xp.z, bA[1]));
            const float b2 = fmaf(wxA1[2], xp.w, fmaf(wxA0[2], xp.z, bA[2]));
            const float b3 = fmaf(wxA1[3], xp.w, fmaf(wxA0[3], xp.z, bA[3]));
            const float4 ha = *reinterpret_cast<const float4*>(&hbuf[rbase]);
            const float4 hb = *reinterpret_cast<const float4*>(&hbuf[rbase + 4]);
            const float2 hc = *reinterpret_cast<const float2*>(&hbuf[rbase + 8]);
            const v2f h01 = (v2f){ha.x, ha.y}, h23 = (v2f){ha.z, ha.w};
            const v2f h45 = (v2f){hb.x, hb.y}, h67 = (v2f){hb.z, hb.w};
            const v2f h89 = (v2f){hc.x, hc.y};

            v2f a0 = pk_mul(wA2[0][0], h01);
            v2f a1 = pk_mul(wA2[1][0], h01);
            v2f a2 = pk_mul(wA2[2][0], h01);
            v2f a3 = pk_mul(wA2[3][0], h01);
            a0 = pk_fma(wA2[0][1], h23, a0); a1 = pk_fma(wA2[1][1], h23, a1);
            a2 = pk_fma(wA2[2][1], h23, a2); a3 = pk_fma(wA2[3][1], h23, a3);
            a0 = pk_fma(wA2[0][2], h45, a0); a1 = pk_fma(wA2[1][2], h45, a1);
            a2 = pk_fma(wA2[2][2], h45, a2); a3 = pk_fma(wA2[3][2], h45, a3);
            a0 = pk_fma(wA2[0][3], h67, a0); a1 = pk_fma(wA2[1][3], h67, a1);
            a2 = pk_fma(wA2[2][3], h67, a2); a3 = pk_fma(wA2[3][3], h67, a3);
            a0 = pk_fma(wA2[0][4], h89, a0); a1 = pk_fma(wA2[1][4], h89, a1);
            a2 = pk_fma(wA2[2][4], h89, a2); a3 = pk_fma(wA2[3][4], h89, a3);

            const float y0 = (a0.x + a0.y) + b0;
            const float y1 = (a1.x + a1.y) + b1;
            const float y2 = (a2.x + a2.y) + b2;
            const float y3 = (a3.x + a3.y) + b3;

            const float ef = EXP2(y1);
            const float ei = EXP2(y0);
            const float eg = EXP2(-__builtin_fabsf(y2));
            const float eo = EXP2(y3);
            const float opf = 1.0f + ef;
            const float d1 = (1.0f + ei) * (1.0f + eg);
            const float tg = __builtin_copysignf((1.0f - eg) * opf, y2);
            const float num = fmaf(c, d1, tg);
            const float cn = num * fast_rcp(opf * d1);
            const float ec = EXP2((-2.0f * LOG2E) * __builtin_fabsf(cn));
            const float d2 = (1.0f + eo) * (1.0f + ec);
            h = __builtin_copysignf((1.0f - ec) * fast_rcp(d2), cn);
            c = cn;
        }

        xp = xnext;
    }

    // ---- output: sigmoid(h . Wlin + blin), reduce across the 10-lane group ----
    {
        const float v = Wlin[jj] * h;
        hbuf[waddr] = v;
        const float4 ha = *reinterpret_cast<const float4*>(&hbuf[rbase]);
        const float4 hb = *reinterpret_cast<const float4*>(&hbuf[rbase + 4]);
        const float2 hc = *reinterpret_cast<const float2*>(&hbuf[rbase + 8]);
        const float s = ((ha.x + ha.y) + (ha.z + ha.w)) +
                        ((hb.x + hb.y) + (hb.z + hb.w)) + (hc.x + hc.y);
        if (valid && j == 0) {
            const float y = s + blin[0];
            out[elem] = fast_rcp(1.0f + EXP2(-LOG2E * y));
        }
    }
}

extern "C" void kernel_launch(void* const* d_in, const int* in_sizes, int n_in,
                              void* d_out, int out_size, void* d_ws, size_t ws_size,
                              hipStream_t stream) {
    const float* x    = (const float*)d_in[0];
    const float* WihA = (const float*)d_in[1];
    const float* WhhA = (const float*)d_in[2];
    const float* bihA = (const float*)d_in[3];
    const float* bhhA = (const float*)d_in[4];
    const float* WihB = (const float*)d_in[5];
    const float* WhhB = (const float*)d_in[6];
    const float* bihB = (const float*)d_in[7];
    const float* bhhB = (const float*)d_in[8];
    const float* Wlin = (const float*)d_in[9];
    const float* blin = (const float*)d_in[10];
    float* out = (float*)d_out;

    const int grid = (BATCH + EPW - 1) / EPW;  // 2731 one-wave blocks
    hipLaunchKernelGGL(lstm_kernel, dim3(grid), dim3(64), 0, stream,
                       x, WihA, WhhA, bihA, bhhA, WihB, WhhB, bihB, bhhB,
                       Wlin, blin, out);
}